// Round 9
// baseline (1379.189 us; speedup 1.0000x reference)
//
#include <hip/hip_runtime.h>

typedef float f32x4 __attribute__((ext_vector_type(4)));

#define B_  512
#define T_  64
#define N_  30
#define FIN 512
#define D_  256
#define C_  7
#define NN  900

// 10 waves: w0..7 GEMM = 4 K-quarters (kq) x 2 col-halves (cgrp);
//           w8..9 stream graph_sigs mean (HBM) -> adjS.
// GEMM lane: 15 rows x 4 cols x 128 K. acc = 15 x f32x4 = 60 VGPR.
// Key fix vs R7: GEMM waves issue ONLY L2-class loads (W + real). The gs
// HBM stream lives in waves 8-9, so in-order vmcnt retirement never makes
// FMA operand waits block on ~900-cycle HBM loads (m135 semantics).
__global__ __launch_bounds__(640, 5)
void digcn_fused(const float* __restrict__ real,
                 const float* __restrict__ gs,
                 const float* __restrict__ W,
                 const float* __restrict__ conv_bias,
                 const float* __restrict__ pool_w,
                 const float* __restrict__ pool_b,
                 const float* __restrict__ head_w,
                 const float* __restrict__ head_b,
                 float* __restrict__ out)
{
    __shared__ __align__(16) float xwS[N_ * D_];     // 30720 B
    __shared__ __align__(16) float adjS[32 * 32];    // 4096 B
    __shared__ float scoreS[4 * 32];
    __shared__ float sumS[32];
    __shared__ float logitS[8];

    const int tid = threadIdx.x;
    const int b   = blockIdx.x;
    const int w   = tid >> 6;            // 0..9
    const int l   = tid & 63;

    const float* gsb = gs + (size_t)b * (T_ * NN);

    if (w < 8) {
        // ================= GEMM waves =================
        const int kq   = w & 3;              // K-quarter [kq*128, kq*128+128)
        const int cgrp = w >> 2;             // col-half
        const int rh   = l >> 5;             // lanes 0-31: rows 0-14; 32-63: rows 15-29
        const int lc   = l & 31;
        const int c0   = cgrp * 128 + lc * 4;

        const float* rB = real + (size_t)b * (N_ * FIN) + (rh * 15) * FIN + kq * 128;
        const float* Wb = W + (size_t)(kq * 128) * D_ + c0;

        f32x4 acc[15];
        #pragma unroll
        for (int rr = 0; rr < 15; ++rr) acc[rr] = (f32x4){0.f, 0.f, 0.f, 0.f};

        #pragma unroll 2
        for (int it = 0; it < 32; ++it) {    // 4 k-values per chunk
            const float* Wit = Wb + it * 4 * D_;
            f32x4 wv0 = *(const f32x4*)(Wit);
            f32x4 wv1 = *(const f32x4*)(Wit + D_);
            f32x4 wv2 = *(const f32x4*)(Wit + 2 * D_);
            f32x4 wv3 = *(const f32x4*)(Wit + 3 * D_);
            const float* rp = rB + it * 4;
            #pragma unroll
            for (int rr = 0; rr < 15; ++rr) {
                f32x4 rv = *(const f32x4*)(rp + rr * FIN);   // 2-addr broadcast
                acc[rr] += wv0 * rv[0];
                acc[rr] += wv1 * rv[1];
                acc[rr] += wv2 * rv[2];
                acc[rr] += wv3 * rv[3];
            }
        }

        // staged K-quarter reduction into xwS (4 barriers, all threads reach below)
        #pragma unroll
        for (int step = 0; step < 4; ++step) {
            if (kq == step) {
                #pragma unroll
                for (int rr = 0; rr < 15; ++rr) {
                    float* p = xwS + (rh * 15 + rr) * D_ + c0;
                    if (step == 0) {
                        *(f32x4*)p = acc[rr];
                    } else {
                        *(f32x4*)p = *(const f32x4*)p + acc[rr];
                    }
                }
            }
            __syncthreads();
        }
    } else {
        // ================= gs streaming waves =================
        const int ws = w - 8;                 // 0,1
        const int q0 = ws * 64 + l;           // quad indices into the 225-quad slice
        const int q1 = q0 + 128;
        const bool v1 = q1 < 225;
        const int q1c = v1 ? q1 : 224;        // clamp: read valid data, discard later

        f32x4 s0 = (f32x4){0.f, 0.f, 0.f, 0.f};
        f32x4 s1 = (f32x4){0.f, 0.f, 0.f, 0.f};
        const float* g0 = gsb + q0 * 4;
        const float* g1 = gsb + q1c * 4;
        #pragma unroll 4
        for (int t = 0; t < T_; ++t) {
            s0 += *(const f32x4*)(g0 + t * NN);
            s1 += *(const f32x4*)(g1 + t * NN);
        }
        s0 *= (1.f / (float)T_);
        s1 *= (1.f / (float)T_);
        #pragma unroll
        for (int c = 0; c < 4; ++c) {
            int e = q0 * 4 + c;
            int i = e / N_, j = e - i * N_;
            adjS[i * 32 + j] = s0[c];
        }
        if (v1) {
            #pragma unroll
            for (int c = 0; c < 4; ++c) {
                int e = q1 * 4 + c;
                int i = e / N_, j = e - i * N_;
                adjS[i * 32 + j] = s1[c];
            }
        }
        if (ws == 0 && l < 60)                // zero pad cols 30,31
            adjS[(l >> 1) * 32 + 30 + (l & 1)] = 0.f;
        // match the GEMM waves' 4 combine barriers
        __syncthreads();
        __syncthreads();
        __syncthreads();
        __syncthreads();
    }

    // ---- P3: agg = adj^T @ xw, ReLU, pool (threads 0..255 = waves 0-3) ----
    if (tid < D_) {
        float xcol[N_];
        #pragma unroll
        for (int i = 0; i < N_; ++i) xcol[i] = xwS[i * D_ + tid];   // 2-way alias = free
        const float bias = conv_bias[tid];
        const float pw   = pool_w[tid];

        #pragma unroll
        for (int j0 = 0; j0 < N_ + 2; j0 += 4) {
            f32x4 agg = (f32x4){0.f, 0.f, 0.f, 0.f};
            #pragma unroll
            for (int i = 0; i < N_; ++i) {
                f32x4 a4 = *(const f32x4*)(adjS + i * 32 + j0);     // uniform broadcast
                agg += a4 * xcol[i];
            }
            #pragma unroll
            for (int c = 0; c < 4; ++c) {
                if (j0 + c < N_) {
                    float h = agg[c] + bias;
                    h = h > 0.f ? h : 0.f;
                    float v = h * pw;
                    #pragma unroll
                    for (int m = 32; m >= 1; m >>= 1) v += __shfl_xor(v, m, 64);
                    if ((tid & 63) == 0) scoreS[(tid >> 6) * 32 + j0 + c] = v;
                }
            }
        }
    }
    __syncthreads();

    // ---- P4: combine waves, head matmul, softmax ----
    if (tid < N_)
        sumS[tid] = scoreS[tid] + scoreS[32 + tid] + scoreS[64 + tid] + scoreS[96 + tid]
                  + pool_b[0];
    __syncthreads();
    if (tid < C_) {
        float lg = head_b[tid];
        #pragma unroll
        for (int j = 0; j < N_; ++j) lg += sumS[j] * head_w[tid * N_ + j];
        logitS[tid] = lg;
    }
    __syncthreads();
    if (tid < C_) {
        float m = logitS[0];
        #pragma unroll
        for (int c = 1; c < C_; ++c) m = fmaxf(m, logitS[c]);
        float s = 0.f;
        #pragma unroll
        for (int c = 0; c < C_; ++c) s += expf(logitS[c] - m);
        out[b * C_ + tid] = expf(logitS[tid] - m) / s;
    }
}

extern "C" void kernel_launch(void* const* d_in, const int* in_sizes, int n_in,
                              void* d_out, int out_size, void* d_ws, size_t ws_size,
                              hipStream_t stream) {
    const float* real      = (const float*)d_in[0];
    // d_in[1] (imag) is unused by the forward pass
    const float* gs        = (const float*)d_in[2];
    const float* W         = (const float*)d_in[3];
    const float* conv_bias = (const float*)d_in[4];
    const float* pool_w    = (const float*)d_in[5];
    const float* pool_b    = (const float*)d_in[6];
    const float* head_w    = (const float*)d_in[7];
    const float* head_b    = (const float*)d_in[8];
    float* outp            = (float*)d_out;

    digcn_fused<<<dim3(B_), dim3(640), 0, stream>>>(
        real, gs, W, conv_bias, pool_w, pool_b, head_w, head_b, outp);
}

// Round 11
// 319.131 us; speedup vs baseline: 4.3217x; 4.3217x over previous
//
#include <hip/hip_runtime.h>

typedef float f32x4 __attribute__((ext_vector_type(4)));

#define B_  512
#define T_  64
#define N_  30
#define FIN 512
#define D_  256
#define C_  7
#define NN  900

// ---------------- Kernel A: adj = mean_t(graph_sigs) ----------------
// One thread per f32x4 quad of the output (512*225 = 115200 threads).
// Pure HBM streaming: 118 MB read, 1.8 MB write to ws.
__global__ __launch_bounds__(256)
void adj_mean(const float* __restrict__ gs, float* __restrict__ adj)
{
    const int q  = blockIdx.x * 256 + threadIdx.x;   // 0..115199, exact
    const int b  = q / 225;
    const int qi = q - b * 225;
    const float* p = gs + (size_t)b * (T_ * NN) + qi * 4;
    f32x4 s = (f32x4){0.f, 0.f, 0.f, 0.f};
    #pragma unroll 8
    for (int t = 0; t < T_; ++t)
        s += *(const f32x4*)(p + t * NN);
    s *= (1.f / (float)T_);
    *(f32x4*)(adj + (size_t)b * NN + qi * 4) = s;
}

// ---------------- Kernel B: GEMM + conv-agg + pool + head + softmax ----------------
// Exactly the measured-no-spill R7 structure (VGPR 64), with every gs access
// removed (gs lived in kernel A). GEMM waves issue ONLY L2-class loads, so
// in-order vmcnt retirement never blocks FMA operands on HBM latency.
// 8 waves = 2 K-halves (kq) x 2 overlapping row-groups (g) x 2 col-halves.
__global__ __launch_bounds__(512, 4)
void digcn_fused(const float* __restrict__ real,
                 const float* __restrict__ adj,
                 const float* __restrict__ W,
                 const float* __restrict__ conv_bias,
                 const float* __restrict__ pool_w,
                 const float* __restrict__ pool_b,
                 const float* __restrict__ head_w,
                 const float* __restrict__ head_b,
                 float* __restrict__ out)
{
    __shared__ __align__(16) float xwS[N_ * D_];     // 30720 B
    __shared__ __align__(16) float adjS[32 * 32];    // 4096 B, padded rows
    __shared__ float scoreS[4 * 32];
    __shared__ float sumS[32];
    __shared__ float logitS[8];

    const int tid  = threadIdx.x;
    const int b    = blockIdx.x;
    const int w    = tid >> 6;          // wave 0..7
    const int l    = tid & 63;
    const int kq   = w & 1;             // K-half: [kq*256, kq*256+256)
    const int g    = (w >> 1) & 1;      // row-group start g*14
    const int cgrp = w >> 2;            // col-half
    const int rh   = l >> 5;            // row sub-half
    const int r0   = g * 14 + rh * 8;   // 8 rows: r0..r0+7 (max 29)
    const int c0   = cgrp * 128 + (l & 31) * 4;

    const float* realb = real + (size_t)b * (N_ * FIN) + r0 * FIN + kq * 256;
    const float* adjb  = adj + (size_t)b * NN;
    const float* Wb    = W + (size_t)(kq * 256) * D_ + c0;

    // ---- stage adj into padded LDS (pads zeroed); barrier below covers it ----
    #pragma unroll
    for (int e = tid; e < 1024; e += 512) {
        int i = e >> 5, j = e & 31;
        adjS[e] = (i < N_ && j < N_) ? adjb[i * N_ + j] : 0.f;
    }

    f32x4 acc[8];
    #pragma unroll
    for (int rr = 0; rr < 8; ++rr) acc[rr] = (f32x4){0.f, 0.f, 0.f, 0.f};

    // ---- main loop: 64 chunks x 4 k; 128 v_fma vs 12 VMEM, 0 DS, 0 barriers ----
    for (int it = 0; it < 64; ++it) {
        const float* Wit = Wb + it * 4 * D_;
        f32x4 wv0 = *(const f32x4*)(Wit);
        f32x4 wv1 = *(const f32x4*)(Wit + D_);
        f32x4 wv2 = *(const f32x4*)(Wit + 2 * D_);
        f32x4 wv3 = *(const f32x4*)(Wit + 3 * D_);
        const float* rp = realb + it * 4;
        #pragma unroll
        for (int rr = 0; rr < 8; ++rr) {
            f32x4 rv = *(const f32x4*)(rp + rr * FIN);   // wave-uniform broadcast
            acc[rr] += wv0 * rv[0];
            acc[rr] += wv1 * rv[1];
            acc[rr] += wv2 * rv[2];
            acc[rr] += wv3 * rv[3];
        }
    }

    // ---- xw combine: kq0 writes, kq1 adds (overlap rows 14,15 bit-identical) ----
    if (kq == 0) {
        #pragma unroll
        for (int rr = 0; rr < 8; ++rr)
            *(f32x4*)(xwS + (r0 + rr) * D_ + c0) = acc[rr];
    }
    __syncthreads();
    if (kq == 1) {
        #pragma unroll
        for (int rr = 0; rr < 8; ++rr) {
            int row = r0 + rr;
            if (!(g == 1 && row < 16)) {                 // skip duplicate add on 14,15
                float* p = xwS + row * D_ + c0;
                *(f32x4*)p = *(const f32x4*)p + acc[rr];
            }
        }
    }
    __syncthreads();

    // ---- P3: agg = adj^T @ xw, ReLU, pool (threads 0..255, thread owns d) ----
    if (tid < D_) {
        float xcol[N_];
        #pragma unroll
        for (int i = 0; i < N_; ++i) xcol[i] = xwS[i * D_ + tid];   // lanes stride-1
        const float bias = conv_bias[tid];
        const float pw   = pool_w[tid];

        #pragma unroll
        for (int j0 = 0; j0 < N_ + 2; j0 += 4) {
            f32x4 agg = (f32x4){0.f, 0.f, 0.f, 0.f};
            #pragma unroll
            for (int i = 0; i < N_; ++i) {
                f32x4 a4 = *(const f32x4*)(adjS + i * 32 + j0);     // uniform broadcast
                agg += a4 * xcol[i];
            }
            #pragma unroll
            for (int c = 0; c < 4; ++c) {
                if (j0 + c < N_) {
                    float h = agg[c] + bias;
                    h = h > 0.f ? h : 0.f;
                    float v = h * pw;
                    #pragma unroll
                    for (int m = 32; m >= 1; m >>= 1) v += __shfl_xor(v, m, 64);
                    if (l == 0) scoreS[w * 32 + j0 + c] = v;
                }
            }
        }
    }
    __syncthreads();

    // ---- P4: combine waves, head matmul, softmax ----
    if (tid < N_)
        sumS[tid] = scoreS[tid] + scoreS[32 + tid] + scoreS[64 + tid] + scoreS[96 + tid]
                  + pool_b[0];
    __syncthreads();
    if (tid < C_) {
        float lg = head_b[tid];
        #pragma unroll
        for (int j = 0; j < N_; ++j) lg += sumS[j] * head_w[tid * N_ + j];
        logitS[tid] = lg;
    }
    __syncthreads();
    if (tid < C_) {
        float m = logitS[0];
        #pragma unroll
        for (int c = 1; c < C_; ++c) m = fmaxf(m, logitS[c]);
        float s = 0.f;
        #pragma unroll
        for (int c = 0; c < C_; ++c) s += expf(logitS[c] - m);
        out[b * C_ + tid] = expf(logitS[tid] - m) / s;
    }
}

extern "C" void kernel_launch(void* const* d_in, const int* in_sizes, int n_in,
                              void* d_out, int out_size, void* d_ws, size_t ws_size,
                              hipStream_t stream) {
    const float* real      = (const float*)d_in[0];
    // d_in[1] (imag) is unused by the forward pass
    const float* gs        = (const float*)d_in[2];
    const float* W         = (const float*)d_in[3];
    const float* conv_bias = (const float*)d_in[4];
    const float* pool_w    = (const float*)d_in[5];
    const float* pool_b    = (const float*)d_in[6];
    const float* head_w    = (const float*)d_in[7];
    const float* head_b    = (const float*)d_in[8];
    float* outp            = (float*)d_out;
    float* adjw            = (float*)d_ws;           // 512*900*4 = 1.84 MB

    adj_mean<<<dim3(450), dim3(256), 0, stream>>>(gs, adjw);
    digcn_fused<<<dim3(B_), dim3(512), 0, stream>>>(
        real, adjw, W, conv_bias, pool_w, pool_b, head_w, head_b, outp);
}